// Round 1
// baseline (226.659 us; speedup 1.0000x reference)
//
#include <hip/hip_runtime.h>
#include <hip/hip_bf16.h>
#include <math.h>

// Problem constants
#define NB   2048     // batch
#define ND   1024     // dim
#define INV_TEMP 10.0f
#define LAMBDA_CS 0.5f

using short8  = __attribute__((ext_vector_type(8))) short;
using floatx4 = __attribute__((ext_vector_type(4))) float;

__device__ __forceinline__ ushort f32_to_bf16_rne(float f) {
  union { float f; unsigned u; } v; v.f = f;
  unsigned u = v.u;
  u += 0x7FFFu + ((u >> 16) & 1u);   // round-to-nearest-even
  return (ushort)(u >> 16);
}

// ---------------------------------------------------------------------------
// Kernel 1: row L2-normalize all four matrices -> bf16 M (8192 x 1024), t-order
// t=0: english, t=1: korean, t=2: etok, t=3: ktoe   (matches embs stack order)
// ---------------------------------------------------------------------------
__global__ __launch_bounds__(256) void k_normalize(
    const float* __restrict__ e, const float* __restrict__ k,
    const float* __restrict__ et, const float* __restrict__ kt,
    ushort* __restrict__ M, float* __restrict__ inv_norm)
{
  const int t = blockIdx.y, b = blockIdx.x;
  const float* src = (t == 0) ? e : (t == 1) ? k : (t == 2) ? et : kt;
  const float4* row = (const float4*)(src + (size_t)b * ND);
  float4 v = row[threadIdx.x];
  float ss = v.x*v.x + v.y*v.y + v.z*v.z + v.w*v.w;
  #pragma unroll
  for (int o = 1; o < 64; o <<= 1) ss += __shfl_xor(ss, o);
  __shared__ float red[4];
  if ((threadIdx.x & 63) == 0) red[threadIdx.x >> 6] = ss;
  __syncthreads();
  float inv = 1.0f / sqrtf(red[0] + red[1] + red[2] + red[3]);

  ushort o4[4] = { f32_to_bf16_rne(v.x * inv), f32_to_bf16_rne(v.y * inv),
                   f32_to_bf16_rne(v.z * inv), f32_to_bf16_rne(v.w * inv) };
  ushort* dst = M + ((size_t)t * NB + b) * ND + threadIdx.x * 4;
  *(ushort4*)dst = *(ushort4*)o4;
  if (threadIdx.x == 0) inv_norm[t * NB + b] = inv;
}

// ---------------------------------------------------------------------------
// Kernel 2: cs-regularization loss (fp32), one block per row
// ---------------------------------------------------------------------------
__global__ __launch_bounds__(256) void k_reg(
    const float* __restrict__ e, const float* __restrict__ k,
    const float* __restrict__ et, const float* __restrict__ kt,
    const float* __restrict__ ratios, const float* __restrict__ inv_norm,
    float* __restrict__ reg_sum)
{
  const int b = blockIdx.x, tid = threadIdx.x;
  const float ie  = inv_norm[b];
  const float ik  = inv_norm[NB + b];
  const float iet = inv_norm[2 * NB + b];
  const float ikt = inv_norm[3 * NB + b];
  const float r = ratios[b], rm = 1.0f - r;

  float4 ve  = ((const float4*)(e  + (size_t)b * ND))[tid];
  float4 vk  = ((const float4*)(k  + (size_t)b * ND))[tid];
  float4 vet = ((const float4*)(et + (size_t)b * ND))[tid];
  float4 vkt = ((const float4*)(kt + (size_t)b * ND))[tid];

  float s1 = 0.f, s2 = 0.f;
  {
    float en, kn, d1, d2;
    en = ve.x*ie; kn = vk.x*ik;
    d1 = vet.x*iet - (r*en + rm*kn); d2 = vkt.x*ikt - (rm*en + r*kn);
    s1 += d1*d1; s2 += d2*d2;
    en = ve.y*ie; kn = vk.y*ik;
    d1 = vet.y*iet - (r*en + rm*kn); d2 = vkt.y*ikt - (rm*en + r*kn);
    s1 += d1*d1; s2 += d2*d2;
    en = ve.z*ie; kn = vk.z*ik;
    d1 = vet.z*iet - (r*en + rm*kn); d2 = vkt.z*ikt - (rm*en + r*kn);
    s1 += d1*d1; s2 += d2*d2;
    en = ve.w*ie; kn = vk.w*ik;
    d1 = vet.w*iet - (r*en + rm*kn); d2 = vkt.w*ikt - (rm*en + r*kn);
    s1 += d1*d1; s2 += d2*d2;
  }
  #pragma unroll
  for (int o = 1; o < 64; o <<= 1) { s1 += __shfl_xor(s1, o); s2 += __shfl_xor(s2, o); }
  __shared__ float r1[4], r2[4];
  if ((tid & 63) == 0) { r1[tid >> 6] = s1; r2[tid >> 6] = s2; }
  __syncthreads();
  if (tid == 0) {
    float t1 = r1[0] + r1[1] + r1[2] + r1[3];
    float t2 = r2[0] + r2[1] + r2[2] + r2[3];
    atomicAdd(reg_sum, sqrtf(t1) + sqrtf(t2));
  }
}

// ---------------------------------------------------------------------------
// Kernel 3: fused NT-GEMM + exp + row-sum + diagonal capture
//   A = M[0:4096]  (e rows then k rows), B = M (8192 rows), K = 1024
//   C[i][j] = exp(10 * dot(A_i, M_j)); rowsum[i] += sum_j C; diag captured.
// 128x128 tile, BK=32, 256 threads (4 waves, 2x2 of 64x64), mfma 16x16x32 bf16
// ---------------------------------------------------------------------------
__global__ __launch_bounds__(256) void k_gemm_exp_rowsum(
    const ushort* __restrict__ M,
    float* __restrict__ rowsum,   // [4096]
    float* __restrict__ diag)     // [2][4][2048]  (side, t, n)
{
  __shared__ ushort As[128 * 32];
  __shared__ ushort Bs[128 * 32];

  const int j0 = blockIdx.x * 128;
  const int i0 = blockIdx.y * 128;
  const int tid  = threadIdx.x;
  const int wave = tid >> 6;
  const int lane = tid & 63;
  const int q = lane >> 4;       // quad 0..3
  const int m = lane & 15;       // spatial index within 16
  const int wrow = (wave >> 1) * 64;
  const int wcol = (wave & 1) * 64;

  floatx4 acc[4][4] = {};

  // staging: each wave issues chunks {2w, 2w+1} of A and B.
  // chunk = 16 rows x 64B. lane -> row lane>>2, 16B-subchunk (lane&3),
  // XOR-swizzled by ((row>>1)&3) so ds_read_b128 is only 2-way conflicted.
  const int srow = lane >> 2;
  const int scol = (lane & 3) ^ ((srow >> 1) & 3);
  const int c0 = wave * 2, c1 = c0 + 1;

  const ushort* gA = M + (size_t)i0 * ND;
  const ushort* gB = M + (size_t)j0 * ND;

  // frag LDS offsets (ushort units); swizzle matches staging
  int aoff[4], boff[4];
  #pragma unroll
  for (int x = 0; x < 4; ++x) {
    const int sw = (q ^ ((m >> 1) & 3)) * 8;
    aoff[x] = (wrow + x * 16 + m) * 32 + sw;
    boff[x] = (wcol + x * 16 + m) * 32 + sw;
  }

  for (int k0 = 0; k0 < ND; k0 += 32) {
    __syncthreads();
    {
      const ushort* g = gA + (size_t)(c0 * 16 + srow) * ND + k0 + scol * 8;
      __builtin_amdgcn_global_load_lds(
          (const __attribute__((address_space(1))) unsigned int*)g,
          (__attribute__((address_space(3))) unsigned int*)&As[c0 * 512], 16, 0, 0);
    }
    {
      const ushort* g = gA + (size_t)(c1 * 16 + srow) * ND + k0 + scol * 8;
      __builtin_amdgcn_global_load_lds(
          (const __attribute__((address_space(1))) unsigned int*)g,
          (__attribute__((address_space(3))) unsigned int*)&As[c1 * 512], 16, 0, 0);
    }
    {
      const ushort* g = gB + (size_t)(c0 * 16 + srow) * ND + k0 + scol * 8;
      __builtin_amdgcn_global_load_lds(
          (const __attribute__((address_space(1))) unsigned int*)g,
          (__attribute__((address_space(3))) unsigned int*)&Bs[c0 * 512], 16, 0, 0);
    }
    {
      const ushort* g = gB + (size_t)(c1 * 16 + srow) * ND + k0 + scol * 8;
      __builtin_amdgcn_global_load_lds(
          (const __attribute__((address_space(1))) unsigned int*)g,
          (__attribute__((address_space(3))) unsigned int*)&Bs[c1 * 512], 16, 0, 0);
    }
    __syncthreads();

    short8 af[4], bf[4];
    #pragma unroll
    for (int x = 0; x < 4; ++x) {
      af[x] = *(const short8*)&As[aoff[x]];
      bf[x] = *(const short8*)&Bs[boff[x]];
    }
    #pragma unroll
    for (int mi = 0; mi < 4; ++mi)
      #pragma unroll
      for (int ni = 0; ni < 4; ++ni)
        acc[mi][ni] = __builtin_amdgcn_mfma_f32_16x16x32_bf16(
            af[mi], bf[ni], acc[mi][ni], 0, 0, 0);
  }

  // Epilogue: v = exp(10*dot); per-row sums + diagonal capture.
  // C/D layout: col = lane&15, row = q*4 + reg   [m89/m91 verified]
  #pragma unroll
  for (int mi = 0; mi < 4; ++mi) {
    #pragma unroll
    for (int r = 0; r < 4; ++r) {
      const int ig = i0 + wrow + mi * 16 + q * 4 + r;
      float s = 0.f;
      #pragma unroll
      for (int ni = 0; ni < 4; ++ni) {
        float v = expf(acc[mi][ni][r] * INV_TEMP);
        s += v;
        const int jg = j0 + wcol + ni * 16 + m;
        if ((jg & (NB - 1)) == (ig & (NB - 1))) {
          // side = ig>>11 (0:e-rows, 1:k-rows), t = jg>>11
          diag[(((ig >> 11) << 2) + (jg >> 11)) * NB + (ig & (NB - 1))] = v;
        }
      }
      s += __shfl_xor(s, 1);
      s += __shfl_xor(s, 2);
      s += __shfl_xor(s, 4);
      s += __shfl_xor(s, 8);
      if (m == 0) atomicAdd(&rowsum[ig], s);
    }
  }
}

// ---------------------------------------------------------------------------
// Kernel 4: final losses
// ---------------------------------------------------------------------------
__global__ __launch_bounds__(256) void k_final(
    const float* __restrict__ rowsum, const float* __restrict__ diag,
    const float* __restrict__ reg_sum, float* __restrict__ out)
{
  float local = 0.f;
  for (int b = threadIdx.x; b < NB; b += 256) {
    float de0 = diag[b],           de1 = diag[NB + b];
    float de2 = diag[2 * NB + b],  de3 = diag[3 * NB + b];
    float num_e = de1 + de2 + de3;
    float den_e = rowsum[b] - de0;            // num_e + neg_e
    float dk0 = diag[4 * NB + b], dk1 = diag[5 * NB + b];
    float dk2 = diag[6 * NB + b], dk3 = diag[7 * NB + b];
    float num_k = dk0 + dk2 + dk3;
    float den_k = rowsum[NB + b] - dk1;       // num_k + neg_k
    local += logf(den_e / num_e) + logf(den_k / num_k);
  }
  #pragma unroll
  for (int o = 1; o < 64; o <<= 1) local += __shfl_xor(local, o);
  __shared__ float red[4];
  if ((threadIdx.x & 63) == 0) red[threadIdx.x >> 6] = local;
  __syncthreads();
  if (threadIdx.x == 0) {
    float contrastive = (red[0] + red[1] + red[2] + red[3]) * (1.0f / (2.0f * NB));
    float cs = reg_sum[0] * (1.0f / NB);
    out[0] = contrastive + LAMBDA_CS * cs;
    out[1] = contrastive;
    out[2] = cs;
  }
}

// ---------------------------------------------------------------------------
extern "C" void kernel_launch(void* const* d_in, const int* in_sizes, int n_in,
                              void* d_out, int out_size, void* d_ws, size_t ws_size,
                              hipStream_t stream) {
  const float* english = (const float*)d_in[0];
  const float* etok    = (const float*)d_in[1];
  const float* ktoe    = (const float*)d_in[2];
  const float* korean  = (const float*)d_in[3];
  const float* ratios  = (const float*)d_in[4];

  char* ws = (char*)d_ws;
  const size_t OFF_M    = 0;                       // 8192*1024*2 = 16777216
  const size_t OFF_INV  = OFF_M + (size_t)8192 * 1024 * 2;   // 4*2048*4 = 32768
  const size_t OFF_DIAG = OFF_INV + 4 * NB * sizeof(float);  // 8*2048*4 = 65536
  const size_t OFF_RS   = OFF_DIAG + 8 * NB * sizeof(float); // 4096*4 = 16384
  const size_t OFF_REG  = OFF_RS + 4096 * sizeof(float);     // 4

  ushort* M       = (ushort*)(ws + OFF_M);
  float* inv_norm = (float*)(ws + OFF_INV);
  float* diag     = (float*)(ws + OFF_DIAG);
  float* rowsum   = (float*)(ws + OFF_RS);
  float* reg_sum  = (float*)(ws + OFF_REG);

  // zero the accumulators (rowsum + reg_sum are contiguous)
  hipMemsetAsync(rowsum, 0, 4096 * sizeof(float) + sizeof(float), stream);

  k_normalize<<<dim3(NB, 4), 256, 0, stream>>>(english, korean, etok, ktoe, M, inv_norm);
  k_reg<<<dim3(NB), 256, 0, stream>>>(english, korean, etok, ktoe, ratios, inv_norm, reg_sum);
  k_gemm_exp_rowsum<<<dim3(64, 32), 256, 0, stream>>>(M, rowsum, diag);
  k_final<<<dim3(1), 256, 0, stream>>>(rowsum, diag, reg_sum, (float*)d_out);
}

// Round 2
// 166.760 us; speedup vs baseline: 1.3592x; 1.3592x over previous
//
#include <hip/hip_runtime.h>
#include <hip/hip_bf16.h>
#include <math.h>

// Problem constants
#define NB   2048     // batch
#define ND   1024     // dim
#define INV_TEMP 10.0f
#define LAMBDA_CS 0.5f

using short8  = __attribute__((ext_vector_type(8))) short;
using floatx4 = __attribute__((ext_vector_type(4))) float;

__device__ __forceinline__ ushort f32_to_bf16_rne(float f) {
  union { float f; unsigned u; } v; v.f = f;
  unsigned u = v.u;
  u += 0x7FFFu + ((u >> 16) & 1u);   // round-to-nearest-even
  return (ushort)(u >> 16);
}

// ---------------------------------------------------------------------------
// Kernel 1: fused row L2-normalize (-> bf16 M, t-order {e,k,et,kt}) + cs-reg
// partial per row. One block per row b; each thread holds one float4 per mat.
// ---------------------------------------------------------------------------
__global__ __launch_bounds__(256) void k_norm_reg(
    const float* __restrict__ e, const float* __restrict__ k,
    const float* __restrict__ et, const float* __restrict__ kt,
    const float* __restrict__ ratios,
    ushort* __restrict__ M, float* __restrict__ reg_partial)
{
  const int b = blockIdx.x, tid = threadIdx.x;
  const int wave = tid >> 6, lane = tid & 63;

  float4 ve  = ((const float4*)(e  + (size_t)b * ND))[tid];
  float4 vk  = ((const float4*)(k  + (size_t)b * ND))[tid];
  float4 vet = ((const float4*)(et + (size_t)b * ND))[tid];
  float4 vkt = ((const float4*)(kt + (size_t)b * ND))[tid];

  float s0 = ve.x*ve.x + ve.y*ve.y + ve.z*ve.z + ve.w*ve.w;
  float s1 = vk.x*vk.x + vk.y*vk.y + vk.z*vk.z + vk.w*vk.w;
  float s2 = vet.x*vet.x + vet.y*vet.y + vet.z*vet.z + vet.w*vet.w;
  float s3 = vkt.x*vkt.x + vkt.y*vkt.y + vkt.z*vkt.z + vkt.w*vkt.w;
  #pragma unroll
  for (int o = 1; o < 64; o <<= 1) {
    s0 += __shfl_xor(s0, o); s1 += __shfl_xor(s1, o);
    s2 += __shfl_xor(s2, o); s3 += __shfl_xor(s3, o);
  }
  __shared__ float red[4][4];
  if (lane == 0) { red[wave][0] = s0; red[wave][1] = s1; red[wave][2] = s2; red[wave][3] = s3; }
  __syncthreads();
  const float ie  = 1.0f / sqrtf(red[0][0] + red[1][0] + red[2][0] + red[3][0]);
  const float ik  = 1.0f / sqrtf(red[0][1] + red[1][1] + red[2][1] + red[3][1]);
  const float iet = 1.0f / sqrtf(red[0][2] + red[1][2] + red[2][2] + red[3][2]);
  const float ikt = 1.0f / sqrtf(red[0][3] + red[1][3] + red[2][3] + red[3][3]);

  // write normalized bf16 rows, t order {0:e, 1:k, 2:et, 3:kt}
  {
    ushort o4[4];
    o4[0] = f32_to_bf16_rne(ve.x * ie);  o4[1] = f32_to_bf16_rne(ve.y * ie);
    o4[2] = f32_to_bf16_rne(ve.z * ie);  o4[3] = f32_to_bf16_rne(ve.w * ie);
    *(ushort4*)(M + ((size_t)0 * NB + b) * ND + tid * 4) = *(ushort4*)o4;
    o4[0] = f32_to_bf16_rne(vk.x * ik);  o4[1] = f32_to_bf16_rne(vk.y * ik);
    o4[2] = f32_to_bf16_rne(vk.z * ik);  o4[3] = f32_to_bf16_rne(vk.w * ik);
    *(ushort4*)(M + ((size_t)1 * NB + b) * ND + tid * 4) = *(ushort4*)o4;
    o4[0] = f32_to_bf16_rne(vet.x * iet); o4[1] = f32_to_bf16_rne(vet.y * iet);
    o4[2] = f32_to_bf16_rne(vet.z * iet); o4[3] = f32_to_bf16_rne(vet.w * iet);
    *(ushort4*)(M + ((size_t)2 * NB + b) * ND + tid * 4) = *(ushort4*)o4;
    o4[0] = f32_to_bf16_rne(vkt.x * ikt); o4[1] = f32_to_bf16_rne(vkt.y * ikt);
    o4[2] = f32_to_bf16_rne(vkt.z * ikt); o4[3] = f32_to_bf16_rne(vkt.w * ikt);
    *(ushort4*)(M + ((size_t)3 * NB + b) * ND + tid * 4) = *(ushort4*)o4;
  }

  // cs-reg partial
  const float r = ratios[b], rm = 1.0f - r;
  float a1 = 0.f, a2 = 0.f;
  {
    float en, kn, d1, d2;
    en = ve.x*ie; kn = vk.x*ik;
    d1 = vet.x*iet - (r*en + rm*kn); d2 = vkt.x*ikt - (rm*en + r*kn);
    a1 += d1*d1; a2 += d2*d2;
    en = ve.y*ie; kn = vk.y*ik;
    d1 = vet.y*iet - (r*en + rm*kn); d2 = vkt.y*ikt - (rm*en + r*kn);
    a1 += d1*d1; a2 += d2*d2;
    en = ve.z*ie; kn = vk.z*ik;
    d1 = vet.z*iet - (r*en + rm*kn); d2 = vkt.z*ikt - (rm*en + r*kn);
    a1 += d1*d1; a2 += d2*d2;
    en = ve.w*ie; kn = vk.w*ik;
    d1 = vet.w*iet - (r*en + rm*kn); d2 = vkt.w*ikt - (rm*en + r*kn);
    a1 += d1*d1; a2 += d2*d2;
  }
  #pragma unroll
  for (int o = 1; o < 64; o <<= 1) { a1 += __shfl_xor(a1, o); a2 += __shfl_xor(a2, o); }
  __shared__ float red2[4][2];
  if (lane == 0) { red2[wave][0] = a1; red2[wave][1] = a2; }
  __syncthreads();
  if (tid == 0) {
    float t1 = red2[0][0] + red2[1][0] + red2[2][0] + red2[3][0];
    float t2 = red2[0][1] + red2[1][1] + red2[2][1] + red2[3][1];
    reg_partial[b] = sqrtf(t1) + sqrtf(t2);
  }
}

// ---------------------------------------------------------------------------
// Kernel 2: fused NT-GEMM + exp + row-sum partials + diagonal capture,
// exploiting symmetry of the left 4096x4096 half (dot(M_i,M_j)=dot(M_j,M_i)).
//   Grid: 1552 blocks = 1024 (right half, bx in [32,64)) + 528 (upper-tri
//   incl diagonal of left half, bx in [by,32)).
//   Off-diagonal triangle blocks also credit COLUMN sums to the mirrored rows.
//   rsp layout: [slot 0..63][row 0..4095]; slot coverage per row-block `by`:
//   direct blocks give slots [by,64), mirrored col-sums give slots [0,by).
// 128x128 tile, BK=32, 256 threads, mfma 16x16x32 bf16. No atomics.
// ---------------------------------------------------------------------------
__global__ __launch_bounds__(256) void k_gemm_exp_rowsum(
    const ushort* __restrict__ M,
    float* __restrict__ rsp,      // [64][4096] partials
    float* __restrict__ diag)     // [2][4][2048]  (side, t, n); [k][0] unused
{
  __shared__ ushort As[128 * 32];
  __shared__ ushort Bs[128 * 32];
  __shared__ float redR[256];
  __shared__ float redC[256];

  // decode (bx, by) from linear block id
  int bx, by;
  {
    int idx = blockIdx.x;
    if (idx < 1024) { by = idx >> 5; bx = 32 + (idx & 31); }
    else {
      int t = idx - 1024; by = 0;
      while (t >= 32 - by) { t -= 32 - by; ++by; }
      bx = by + t;
    }
  }
  const bool sym = (bx < 32) && (bx > by);
  const int j0 = bx * 128;
  const int i0 = by * 128;

  const int tid  = threadIdx.x;
  const int wave = tid >> 6;
  const int lane = tid & 63;
  const int q = lane >> 4;       // quad 0..3
  const int m = lane & 15;       // spatial index within 16
  const int wrow = (wave >> 1) * 64;
  const int wcol = (wave & 1) * 64;

  floatx4 acc[4][4] = {};

  // staging: chunk = 16 rows x 64B; XOR swizzle so ds_read_b128 is 2-way only
  const int srow = lane >> 2;
  const int scol = (lane & 3) ^ ((srow >> 1) & 3);
  const int c0 = wave * 2, c1 = c0 + 1;

  const ushort* gA = M + (size_t)i0 * ND;
  const ushort* gB = M + (size_t)j0 * ND;

  int aoff[4], boff[4];
  #pragma unroll
  for (int x = 0; x < 4; ++x) {
    const int sw = (q ^ ((m >> 1) & 3)) * 8;
    aoff[x] = (wrow + x * 16 + m) * 32 + sw;
    boff[x] = (wcol + x * 16 + m) * 32 + sw;
  }

  for (int k0 = 0; k0 < ND; k0 += 32) {
    __syncthreads();
    {
      const ushort* g = gA + (size_t)(c0 * 16 + srow) * ND + k0 + scol * 8;
      __builtin_amdgcn_global_load_lds(
          (const __attribute__((address_space(1))) unsigned int*)g,
          (__attribute__((address_space(3))) unsigned int*)&As[c0 * 512], 16, 0, 0);
    }
    {
      const ushort* g = gA + (size_t)(c1 * 16 + srow) * ND + k0 + scol * 8;
      __builtin_amdgcn_global_load_lds(
          (const __attribute__((address_space(1))) unsigned int*)g,
          (__attribute__((address_space(3))) unsigned int*)&As[c1 * 512], 16, 0, 0);
    }
    {
      const ushort* g = gB + (size_t)(c0 * 16 + srow) * ND + k0 + scol * 8;
      __builtin_amdgcn_global_load_lds(
          (const __attribute__((address_space(1))) unsigned int*)g,
          (__attribute__((address_space(3))) unsigned int*)&Bs[c0 * 512], 16, 0, 0);
    }
    {
      const ushort* g = gB + (size_t)(c1 * 16 + srow) * ND + k0 + scol * 8;
      __builtin_amdgcn_global_load_lds(
          (const __attribute__((address_space(1))) unsigned int*)g,
          (__attribute__((address_space(3))) unsigned int*)&Bs[c1 * 512], 16, 0, 0);
    }
    __syncthreads();

    short8 af[4], bf[4];
    #pragma unroll
    for (int x = 0; x < 4; ++x) {
      af[x] = *(const short8*)&As[aoff[x]];
      bf[x] = *(const short8*)&Bs[boff[x]];
    }
    #pragma unroll
    for (int mi = 0; mi < 4; ++mi)
      #pragma unroll
      for (int ni = 0; ni < 4; ++ni)
        acc[mi][ni] = __builtin_amdgcn_mfma_f32_16x16x32_bf16(
            af[mi], bf[ni], acc[mi][ni], 0, 0, 0);
  }

  // Epilogue. C/D layout: col = lane&15, row = q*4 + reg  [m89/m91]
  float colAcc[4] = {0.f, 0.f, 0.f, 0.f};
  #pragma unroll
  for (int mi = 0; mi < 4; ++mi) {
    #pragma unroll
    for (int r = 0; r < 4; ++r) {
      const int ig = i0 + wrow + mi * 16 + q * 4 + r;
      float s = 0.f;
      #pragma unroll
      for (int ni = 0; ni < 4; ++ni) {
        float v = __expf(acc[mi][ni][r] * INV_TEMP);
        s += v;
        colAcc[ni] += v;
        const int jg = j0 + wcol + ni * 16 + m;
        if ((jg & (NB - 1)) == (ig & (NB - 1))) {
          diag[(((ig >> 11) << 2) + (jg >> 11)) * NB + (ig & (NB - 1))] = v;
        }
      }
      s += __shfl_xor(s, 1);
      s += __shfl_xor(s, 2);
      s += __shfl_xor(s, 4);
      s += __shfl_xor(s, 8);
      if (m == 0) redR[(wave & 1) * 128 + wrow + mi * 16 + q * 4 + r] = s;
    }
  }
  #pragma unroll
  for (int ni = 0; ni < 4; ++ni) {
    float c = colAcc[ni];
    c += __shfl_xor(c, 16);
    c += __shfl_xor(c, 32);
    if (q == 0) redC[(wave >> 1) * 128 + wcol + ni * 16 + m] = c;
  }
  __syncthreads();
  if (tid < 128) {
    rsp[(size_t)bx * 4096 + i0 + tid] = redR[tid] + redR[128 + tid];
    if (sym)
      rsp[(size_t)by * 4096 + j0 + tid] = redC[tid] + redC[128 + tid];
  }
}

// ---------------------------------------------------------------------------
// Kernel 3: per-row losses (reduce 64 partials per row; diag mirror for k.e)
// ---------------------------------------------------------------------------
__global__ __launch_bounds__(256) void k_rowloss(
    const float* __restrict__ rsp, const float* __restrict__ diag,
    float* __restrict__ loss_row)
{
  const int n = blockIdx.x * 256 + threadIdx.x;  // 0..2047
  float se = 0.f, sk = 0.f;
  #pragma unroll 8
  for (int s = 0; s < 64; ++s) {
    se += rsp[s * 4096 + n];
    sk += rsp[s * 4096 + 2048 + n];
  }
  const float d_ee  = diag[0 * NB + n];
  const float d_ek  = diag[1 * NB + n];
  const float d_eet = diag[2 * NB + n];
  const float d_ekt = diag[3 * NB + n];
  const float d_kk  = diag[5 * NB + n];
  const float d_ket = diag[6 * NB + n];
  const float d_kkt = diag[7 * NB + n];
  const float num_e = d_ek + d_eet + d_ekt;
  const float den_e = se - d_ee;
  const float num_k = d_ek + d_ket + d_kkt;   // k.e diag == e.k diag (mirror)
  const float den_k = sk - d_kk;
  loss_row[n] = logf(den_e / num_e) + logf(den_k / num_k);
}

// ---------------------------------------------------------------------------
// Kernel 4: final scalar outputs
// ---------------------------------------------------------------------------
__global__ __launch_bounds__(256) void k_out(
    const float* __restrict__ loss_row, const float* __restrict__ reg_partial,
    float* __restrict__ out)
{
  const int tid = threadIdx.x;
  const int wave = tid >> 6, lane = tid & 63;
  float l = 0.f, g = 0.f;
  #pragma unroll
  for (int i = 0; i < 8; ++i) {
    l += loss_row[tid + i * 256];
    g += reg_partial[tid + i * 256];
  }
  #pragma unroll
  for (int o = 1; o < 64; o <<= 1) { l += __shfl_xor(l, o); g += __shfl_xor(g, o); }
  __shared__ float rl[4], rg[4];
  if (lane == 0) { rl[wave] = l; rg[wave] = g; }
  __syncthreads();
  if (tid == 0) {
    float contrastive = (rl[0] + rl[1] + rl[2] + rl[3]) * (1.0f / (2.0f * NB));
    float cs = (rg[0] + rg[1] + rg[2] + rg[3]) * (1.0f / NB);
    out[0] = contrastive + LAMBDA_CS * cs;
    out[1] = contrastive;
    out[2] = cs;
  }
}

// ---------------------------------------------------------------------------
extern "C" void kernel_launch(void* const* d_in, const int* in_sizes, int n_in,
                              void* d_out, int out_size, void* d_ws, size_t ws_size,
                              hipStream_t stream) {
  const float* english = (const float*)d_in[0];
  const float* etok    = (const float*)d_in[1];
  const float* ktoe    = (const float*)d_in[2];
  const float* korean  = (const float*)d_in[3];
  const float* ratios  = (const float*)d_in[4];

  char* ws = (char*)d_ws;
  const size_t OFF_M    = 0;                                   // 16777216 B
  const size_t OFF_RSP  = OFF_M + (size_t)8192 * 1024 * 2;     // 64*4096*4 = 1 MB
  const size_t OFF_DIAG = OFF_RSP + (size_t)64 * 4096 * 4;     // 8*2048*4
  const size_t OFF_REG  = OFF_DIAG + 8 * NB * sizeof(float);   // 2048*4
  const size_t OFF_LOSS = OFF_REG + NB * sizeof(float);        // 2048*4

  ushort* M           = (ushort*)(ws + OFF_M);
  float* rsp          = (float*)(ws + OFF_RSP);
  float* diag         = (float*)(ws + OFF_DIAG);
  float* reg_partial  = (float*)(ws + OFF_REG);
  float* loss_row     = (float*)(ws + OFF_LOSS);

  k_norm_reg<<<dim3(NB), 256, 0, stream>>>(english, korean, etok, ktoe, ratios, M, reg_partial);
  k_gemm_exp_rowsum<<<dim3(1552), 256, 0, stream>>>(M, rsp, diag);
  k_rowloss<<<dim3(8), 256, 0, stream>>>(rsp, diag, loss_row);
  k_out<<<dim3(1), 256, 0, stream>>>(loss_row, reg_partial, (float*)d_out);
}